// Round 6
// baseline (818.692 us; speedup 1.0000x reference)
//
#include <hip/hip_runtime.h>

// ---------------------------------------------------------------------------
// 3-layer GCN, reassociated:  Z_{l+1} = relu( (A_hat · Z_l) @ W_l + b_l )
// A_hat = D^-1/2 (A+I) D^-1/2. CSR gather aggregation (no hot-path atomics).
// FUSED per layer: gather-aggregate -> LDS (split bf16 hi/lo) -> MFMA GEMM
// (3-pass hi/lo emulation of fp32, err ~2^-16) -> bias+ReLU -> fp32 out.
// ---------------------------------------------------------------------------

typedef __bf16 bf16x8 __attribute__((ext_vector_type(8)));
typedef float  f32x4  __attribute__((ext_vector_type(4)));
typedef unsigned short ushort_t;
typedef unsigned int   uint_t;

__device__ __forceinline__ ushort_t f2bf(float f) {
    uint_t u = __builtin_bit_cast(uint_t, f);
    u += 0x7FFFu + ((u >> 16) & 1u);       // RNE
    return (ushort_t)(u >> 16);
}
__device__ __forceinline__ float bf2f(ushort_t h) {
    uint_t u = ((uint_t)h) << 16;
    return __builtin_bit_cast(float, u);
}

// ---- edge dtype detection: int64 edges have all-zero high words ------------
__global__ void k_detect(const int* __restrict__ ei, int E, int* __restrict__ flag) {
    __shared__ int nonzero;
    if (threadIdx.x == 0) nonzero = 0;
    __syncthreads();
    size_t k = (size_t)threadIdx.x * (size_t)E / 256;
    if (ei[2 * k + 1] != 0) atomicOr(&nonzero, 1);
    __syncthreads();
    if (threadIdx.x == 0) *flag = (nonzero == 0) ? 1 : 0;   // 1 => int64
}

__global__ __launch_bounds__(256) void k_convert(const int* __restrict__ ei, int E,
                                                 const int* __restrict__ flag,
                                                 int* __restrict__ src32,
                                                 int* __restrict__ dst32) {
    int is64 = *flag;
    for (int e = blockIdx.x * 256 + threadIdx.x; e < E; e += gridDim.x * 256) {
        if (is64) {
            const long long* p = (const long long*)ei;
            src32[e] = (int)p[e];
            dst32[e] = (int)p[(size_t)E + e];
        } else {
            src32[e] = ei[e];
            dst32[e] = ei[(size_t)E + e];
        }
    }
}

__global__ __launch_bounds__(256) void k_zero_int(int* __restrict__ p, int n) {
    for (int i = blockIdx.x * 256 + threadIdx.x; i < n; i += gridDim.x * 256) p[i] = 0;
}

__global__ __launch_bounds__(256) void k_count(const int* __restrict__ dst,
                                               int* __restrict__ indeg, int E) {
    for (int e = blockIdx.x * 256 + threadIdx.x; e < E; e += gridDim.x * 256)
        atomicAdd(&indeg[dst[e]], 1);
}

__global__ __launch_bounds__(256) void k_dinv(const int* __restrict__ indeg,
                                              float* __restrict__ dinv, int N) {
    int i = blockIdx.x * 256 + threadIdx.x;
    if (i < N) dinv[i] = rsqrtf(1.0f + (float)indeg[i]);   // +1 self-loop
}

// ---- exclusive scan of indeg[N] -> rowptr ----------------------------------
__global__ __launch_bounds__(256) void k_scan1(const int* __restrict__ indeg,
                                               int* __restrict__ rowptr,
                                               int* __restrict__ partials, int N) {
    __shared__ int sdata[256];
    const int b = blockIdx.x, t = threadIdx.x;
    const int base = b * 1024 + t * 4;
    int v[4], s = 0;
#pragma unroll
    for (int j = 0; j < 4; ++j) { v[j] = (base + j < N) ? indeg[base + j] : 0; s += v[j]; }
    sdata[t] = s;
    __syncthreads();
    for (int off = 1; off < 256; off <<= 1) {
        int x = (t >= off) ? sdata[t - off] : 0;
        __syncthreads();
        sdata[t] += x;
        __syncthreads();
    }
    int run = (t > 0) ? sdata[t - 1] : 0;
    if (t == 255) partials[b] = sdata[255];
#pragma unroll
    for (int j = 0; j < 4; ++j) {
        if (base + j < N) rowptr[base + j] = run;
        run += v[j];
    }
}

__global__ __launch_bounds__(256) void k_scan2(int* __restrict__ partials, int nb) {
    __shared__ int sdata[256];
    int t = threadIdx.x;
    sdata[t] = (t < nb) ? partials[t] : 0;
    __syncthreads();
    for (int off = 1; off < 256; off <<= 1) {
        int x = (t >= off) ? sdata[t - off] : 0;
        __syncthreads();
        sdata[t] += x;
        __syncthreads();
    }
    if (t < nb) partials[t] = (t > 0) ? sdata[t - 1] : 0;
}

__global__ __launch_bounds__(256) void k_scan3(int* __restrict__ rowptr,
                                               const int* __restrict__ partials,
                                               int N, int E) {
    for (int i = blockIdx.x * 256 + threadIdx.x; i < N; i += gridDim.x * 256)
        rowptr[i] += partials[i >> 10];
    if (blockIdx.x == 0 && threadIdx.x == 0) rowptr[N] = E;
}

__global__ __launch_bounds__(256) void k_fill(const int* __restrict__ src,
                                              const int* __restrict__ dst,
                                              const int* __restrict__ rowptr,
                                              int* __restrict__ fillcnt,
                                              int* __restrict__ colsrc, int E) {
    for (int e = blockIdx.x * 256 + threadIdx.x; e < E; e += gridDim.x * 256) {
        int d = dst[e];
        int pos = rowptr[d] + atomicAdd(&fillcnt[d], 1);
        colsrc[pos] = src[e];
    }
}

// ---- weight transpose + hi/lo split: Wt[n][k] = split(W[k][n]) -------------
__global__ __launch_bounds__(256) void k_wsplit(const float* __restrict__ W,
                                                ushort_t* __restrict__ Wh,
                                                ushort_t* __restrict__ Wl,
                                                int K, int Nn) {
    int idx = blockIdx.x * 256 + threadIdx.x;
    if (idx >= K * Nn) return;
    int k = idx / Nn, n = idx - k * Nn;
    float w = W[idx];
    ushort_t h = f2bf(w);
    ushort_t l = f2bf(w - bf2f(h));
    Wh[(size_t)n * K + k] = h;
    Wl[(size_t)n * K + k] = l;
}

// ---- FUSED: gather-aggregate 64 nodes -> LDS split bf16 -> MFMA GEMM -------
// out[64,256] = relu( (A_hat z)[block rows] @ Wt^T + bias )
// 512 threads = 8 waves. Phase 1: wave w aggregates nodes w*8..w*8+7.
// Phase 2: waves 2x4, wave tile 32 rows x 64 cols = 2x4 MFMA 16x16x32 (x3 split).
template <int C>
__global__ __launch_bounds__(512, 4) void k_fused(
    const float* __restrict__ z, const int* __restrict__ rowptr,
    const int* __restrict__ colsrc, const float* __restrict__ dinv,
    const ushort_t* __restrict__ Bh, const ushort_t* __restrict__ Bl,
    const float* __restrict__ bias, float* __restrict__ outp, int N) {
    constexpr int VE  = C / 64;      // floats per lane in gather (2 or 4)
    constexpr int LDC = C + 8;       // LDS row stride (bank spread)
    __shared__ ushort_t Ash[64][LDC];
    __shared__ ushort_t Asl[64][LDC];

    const int tid  = threadIdx.x;
    const int lane = tid & 63;
    const int wid  = tid >> 6;       // 0..7
    const int nb   = blockIdx.x * 64;

    // ---------------- phase 1: aggregate 8 nodes per wave ----------------
    for (int i = 0; i < 8; ++i) {
        const int row  = wid * 8 + i;
        const int node = nb + row;
        if (node < N) {
            const float di = dinv[node];
            float acc0[VE], acc1[VE];
            {
                const float s2 = di * di;
                const float* zp = &z[(size_t)node * C + lane * VE];
#pragma unroll
                for (int j = 0; j < VE; ++j) { acc0[j] = zp[j] * s2; acc1[j] = 0.f; }
            }
            const int start = rowptr[node], end = rowptr[node + 1];
            for (int base = start; base < end; base += 64) {
                const int rem = end - base;
                int sv = 0; float nv = 0.f;
                if (lane < rem) { sv = colsrc[base + lane]; nv = dinv[sv] * di; }
                const int cnt = rem < 64 ? rem : 64;
                int jj = 0;
                for (; jj + 2 <= cnt; jj += 2) {
                    int   s0 = __shfl(sv, jj),     s1 = __shfl(sv, jj + 1);
                    float n0 = __shfl(nv, jj),     n1 = __shfl(nv, jj + 1);
                    const float* p0 = &z[(size_t)s0 * C + lane * VE];
                    const float* p1 = &z[(size_t)s1 * C + lane * VE];
                    if (VE == 4) {
                        float4 v0 = *(const float4*)p0;
                        float4 v1 = *(const float4*)p1;
                        acc0[0] = fmaf(v0.x, n0, acc0[0]); acc1[0] = fmaf(v1.x, n1, acc1[0]);
                        acc0[1] = fmaf(v0.y, n0, acc0[1]); acc1[1] = fmaf(v1.y, n1, acc1[1]);
                        acc0[2] = fmaf(v0.z, n0, acc0[2]); acc1[2] = fmaf(v1.z, n1, acc1[2]);
                        acc0[3] = fmaf(v0.w, n0, acc0[3]); acc1[3] = fmaf(v1.w, n1, acc1[3]);
                    } else {
                        float2 v0 = *(const float2*)p0;
                        float2 v1 = *(const float2*)p1;
                        acc0[0] = fmaf(v0.x, n0, acc0[0]); acc1[0] = fmaf(v1.x, n1, acc1[0]);
                        acc0[1] = fmaf(v0.y, n0, acc0[1]); acc1[1] = fmaf(v1.y, n1, acc1[1]);
                    }
                }
                if (jj < cnt) {
                    int   s0 = __shfl(sv, jj);
                    float n0 = __shfl(nv, jj);
                    const float* p0 = &z[(size_t)s0 * C + lane * VE];
                    if (VE == 4) {
                        float4 v0 = *(const float4*)p0;
                        acc0[0] = fmaf(v0.x, n0, acc0[0]);
                        acc0[1] = fmaf(v0.y, n0, acc0[1]);
                        acc0[2] = fmaf(v0.z, n0, acc0[2]);
                        acc0[3] = fmaf(v0.w, n0, acc0[3]);
                    } else {
                        float2 v0 = *(const float2*)p0;
                        acc0[0] = fmaf(v0.x, n0, acc0[0]);
                        acc0[1] = fmaf(v0.y, n0, acc0[1]);
                    }
                }
            }
            ushort_t h[VE], l[VE];
#pragma unroll
            for (int j = 0; j < VE; ++j) {
                float a = acc0[j] + acc1[j];
                h[j] = f2bf(a);
                l[j] = f2bf(a - bf2f(h[j]));
            }
            if (VE == 4) {
                uint2 hv, lv;
                hv.x = (uint_t)h[0] | ((uint_t)h[1] << 16);
                hv.y = (uint_t)h[2] | ((uint_t)h[3] << 16);
                lv.x = (uint_t)l[0] | ((uint_t)l[1] << 16);
                lv.y = (uint_t)l[2] | ((uint_t)l[3] << 16);
                *(uint2*)&Ash[row][lane * 4] = hv;
                *(uint2*)&Asl[row][lane * 4] = lv;
            } else {
                *(uint_t*)&Ash[row][lane * 2] = (uint_t)h[0] | ((uint_t)h[1] << 16);
                *(uint_t*)&Asl[row][lane * 2] = (uint_t)l[0] | ((uint_t)l[1] << 16);
            }
        } else {
            if (VE == 4) {
                *(uint2*)&Ash[row][lane * 4] = make_uint2(0, 0);
                *(uint2*)&Asl[row][lane * 4] = make_uint2(0, 0);
            } else {
                *(uint_t*)&Ash[row][lane * 2] = 0;
                *(uint_t*)&Asl[row][lane * 2] = 0;
            }
        }
    }
    __syncthreads();

    // ---------------- phase 2: GEMM 64x256 = A[64,C] @ Wt[256,C]^T ----------
    const int wrow = wid >> 2;       // 0..1  -> rows wrow*32..+31
    const int wcol = wid & 3;        // 0..3  -> cols wcol*64..+63
    f32x4 acc[2][4] = {};

    for (int k0 = 0; k0 < C; k0 += 32) {
        const int acol = k0 + ((lane >> 4) << 3);
        bf16x8 ah[2], al[2];
#pragma unroll
        for (int mt = 0; mt < 2; ++mt) {
            const int r = wrow * 32 + mt * 16 + (lane & 15);
            ah[mt] = *(const bf16x8*)&Ash[r][acol];
            al[mt] = *(const bf16x8*)&Asl[r][acol];
        }
#pragma unroll
        for (int nt = 0; nt < 4; ++nt) {
            const int n = wcol * 64 + nt * 16 + (lane & 15);
            bf16x8 bh = *(const bf16x8*)&Bh[(size_t)n * C + acol];
            bf16x8 bl = *(const bf16x8*)&Bl[(size_t)n * C + acol];
#pragma unroll
            for (int mt = 0; mt < 2; ++mt) {
                acc[mt][nt] = __builtin_amdgcn_mfma_f32_16x16x32_bf16(ah[mt], bh, acc[mt][nt], 0, 0, 0);
                acc[mt][nt] = __builtin_amdgcn_mfma_f32_16x16x32_bf16(ah[mt], bl, acc[mt][nt], 0, 0, 0);
                acc[mt][nt] = __builtin_amdgcn_mfma_f32_16x16x32_bf16(al[mt], bh, acc[mt][nt], 0, 0, 0);
            }
        }
    }

    // epilogue: D layout col=lane&15 (within 16x16), row=(lane>>4)*4+reg
    float bv[4];
#pragma unroll
    for (int nt = 0; nt < 4; ++nt)
        bv[nt] = bias[wcol * 64 + nt * 16 + (lane & 15)];
    const int col0  = wcol * 64 + (lane & 15);
    const int rbase = nb + wrow * 32 + ((lane >> 4) << 2);
#pragma unroll
    for (int mt = 0; mt < 2; ++mt)
#pragma unroll
        for (int j = 0; j < 4; ++j) {
            const int r = rbase + mt * 16 + j;
            if (r < N) {
                float* cp = &outp[(size_t)r * 256 + col0];
#pragma unroll
                for (int nt = 0; nt < 4; ++nt)
                    cp[nt * 16] = fmaxf(acc[mt][nt][j] + bv[nt], 0.f);
            }
        }
}

extern "C" void kernel_launch(void* const* d_in, const int* in_sizes, int n_in,
                              void* d_out, int out_size, void* d_ws, size_t ws_size,
                              hipStream_t stream) {
    const float* x  = (const float*)d_in[0];
    const int*   ei = (const int*)d_in[1];
    const float* W0 = (const float*)d_in[2];
    const float* b0 = (const float*)d_in[3];
    const float* W1 = (const float*)d_in[4];
    const float* b1 = (const float*)d_in[5];
    const float* W2 = (const float*)d_in[6];
    const float* b2 = (const float*)d_in[7];

    const int D = 128, H = 256;
    const int N = in_sizes[0] / D;
    const int E = in_sizes[1] / 2;

    char* ws = (char*)d_ws;
    auto align = [](size_t v) { return (v + 511) & ~(size_t)511; };
    size_t o = 0;
    int*      flag     = (int*)(ws + o);      o += align(sizeof(int));
    float*    dinv     = (float*)(ws + o);    o += align((size_t)N * 4);
    int*      indeg    = (int*)(ws + o);      o += align((size_t)N * 4);
    int*      fillcnt  = (int*)(ws + o);      o += align((size_t)N * 4);
    int*      rowptr   = (int*)(ws + o);      o += align(((size_t)N + 1) * 4);
    int*      partials = (int*)(ws + o);      o += align(256 * 4);
    int*      src32    = (int*)(ws + o);      o += align((size_t)E * 4);
    int*      dst32    = (int*)(ws + o);      o += align((size_t)E * 4);
    int*      colsrc   = (int*)(ws + o);      o += align((size_t)E * 4);
    ushort_t* Wth      = (ushort_t*)(ws + o); o += align((size_t)H * H * 2);
    ushort_t* Wtl      = (ushort_t*)(ws + o); o += align((size_t)H * H * 2);
    ushort_t* Wth2     = (ushort_t*)(ws + o); o += align((size_t)H * H * 2);
    ushort_t* Wtl2     = (ushort_t*)(ws + o); o += align((size_t)H * H * 2);
    ushort_t* Wth3     = (ushort_t*)(ws + o); o += align((size_t)H * H * 2);
    ushort_t* Wtl3     = (ushort_t*)(ws + o); o += align((size_t)H * H * 2);
    float*    bufA     = (float*)(ws + o);    o += align((size_t)N * H * 4);
    float*    bufB     = (float*)(ws + o);    o += align((size_t)N * H * 4);
    float*    out      = (float*)d_out;

    const int nBlkN  = (N + 255) / 256;
    const int nBlkE  = (E + 255) / 256;
    const int nbScan = (N + 1023) / 1024;

    // ---- normalization + CSR build ----
    k_detect<<<1, 256, 0, stream>>>(ei, E, flag);
    k_convert<<<nBlkE, 256, 0, stream>>>(ei, E, flag, src32, dst32);
    k_zero_int<<<nBlkN, 256, 0, stream>>>(indeg, N);
    k_zero_int<<<nBlkN, 256, 0, stream>>>(fillcnt, N);
    k_count<<<nBlkE, 256, 0, stream>>>(dst32, indeg, E);
    k_dinv<<<nBlkN, 256, 0, stream>>>(indeg, dinv, N);
    k_scan1<<<nbScan, 256, 0, stream>>>(indeg, rowptr, partials, N);
    k_scan2<<<1, 256, 0, stream>>>(partials, nbScan);
    k_scan3<<<nBlkN, 256, 0, stream>>>(rowptr, partials, N, E);
    k_fill<<<nBlkE, 256, 0, stream>>>(src32, dst32, rowptr, fillcnt, colsrc, E);

    // ---- weight splits (tiny; all up front) ----
    k_wsplit<<<(D * H + 255) / 256, 256, 0, stream>>>(W0, Wth, Wtl, D, H);
    k_wsplit<<<(H * H + 255) / 256, 256, 0, stream>>>(W1, Wth2, Wtl2, H, H);
    k_wsplit<<<(H * H + 255) / 256, 256, 0, stream>>>(W2, Wth3, Wtl3, H, H);

    const int fusedGrid = (N + 63) / 64;

    // ---- layer 0: x[N,128] -> bufA ----
    k_fused<128><<<fusedGrid, 512, 0, stream>>>(x, rowptr, colsrc, dinv,
                                                Wth, Wtl, b0, bufA, N);
    // ---- layer 1: bufA -> bufB ----
    k_fused<256><<<fusedGrid, 512, 0, stream>>>(bufA, rowptr, colsrc, dinv,
                                                Wth2, Wtl2, b1, bufB, N);
    // ---- layer 2: bufB -> out ----
    k_fused<256><<<fusedGrid, 512, 0, stream>>>(bufB, rowptr, colsrc, dinv,
                                                Wth3, Wtl3, b2, out, N);

    (void)n_in; (void)out_size; (void)ws_size; (void)o;
}

// Round 8
// 701.947 us; speedup vs baseline: 1.1663x; 1.1663x over previous
//
#include <hip/hip_runtime.h>

// ---------------------------------------------------------------------------
// 3-layer GCN, reassociated:  Z_{l+1} = relu( (A_hat · Z_l) @ W_l + b_l )
// A_hat = D^-1/2 (A+I) D^-1/2. CSR gather aggregation (no hot-path atomics),
// edge norms precomputed into CSR (colnorm). Aggregate: 1 wave/node, 4-deep
// unrolled gather (latency hiding), writes split-bf16 hi/lo planes.
// GEMM = split-bf16 MFMA (3-pass hi/lo emulation of fp32, err ~2^-16).
// ---------------------------------------------------------------------------

typedef __bf16 bf16x8 __attribute__((ext_vector_type(8)));
typedef float  f32x4  __attribute__((ext_vector_type(4)));
typedef unsigned short ushort_t;
typedef unsigned int   uint_t;

__device__ __forceinline__ ushort_t f2bf(float f) {
    uint_t u = __builtin_bit_cast(uint_t, f);
    u += 0x7FFFu + ((u >> 16) & 1u);       // RNE
    return (ushort_t)(u >> 16);
}
__device__ __forceinline__ float bf2f(ushort_t h) {
    uint_t u = ((uint_t)h) << 16;
    return __builtin_bit_cast(float, u);
}

// ---- edge dtype detection: int64 edges have all-zero high words ------------
__global__ void k_detect(const int* __restrict__ ei, int E, int* __restrict__ flag) {
    __shared__ int nonzero;
    if (threadIdx.x == 0) nonzero = 0;
    __syncthreads();
    size_t k = (size_t)threadIdx.x * (size_t)E / 256;
    if (ei[2 * k + 1] != 0) atomicOr(&nonzero, 1);
    __syncthreads();
    if (threadIdx.x == 0) *flag = (nonzero == 0) ? 1 : 0;   // 1 => int64
}

__global__ __launch_bounds__(256) void k_convert(const int* __restrict__ ei, int E,
                                                 const int* __restrict__ flag,
                                                 int* __restrict__ src32,
                                                 int* __restrict__ dst32) {
    int is64 = *flag;
    for (int e = blockIdx.x * 256 + threadIdx.x; e < E; e += gridDim.x * 256) {
        if (is64) {
            const long long* p = (const long long*)ei;
            src32[e] = (int)p[e];
            dst32[e] = (int)p[(size_t)E + e];
        } else {
            src32[e] = ei[e];
            dst32[e] = ei[(size_t)E + e];
        }
    }
}

__global__ __launch_bounds__(256) void k_zero_int(int* __restrict__ p, int n) {
    for (int i = blockIdx.x * 256 + threadIdx.x; i < n; i += gridDim.x * 256) p[i] = 0;
}

__global__ __launch_bounds__(256) void k_count(const int* __restrict__ dst,
                                               int* __restrict__ indeg, int E) {
    for (int e = blockIdx.x * 256 + threadIdx.x; e < E; e += gridDim.x * 256)
        atomicAdd(&indeg[dst[e]], 1);
}

__global__ __launch_bounds__(256) void k_dinv(const int* __restrict__ indeg,
                                              float* __restrict__ dinv, int N) {
    int i = blockIdx.x * 256 + threadIdx.x;
    if (i < N) dinv[i] = rsqrtf(1.0f + (float)indeg[i]);   // +1 self-loop
}

// ---- exclusive scan of indeg[N] -> rowptr ----------------------------------
__global__ __launch_bounds__(256) void k_scan1(const int* __restrict__ indeg,
                                               int* __restrict__ rowptr,
                                               int* __restrict__ partials, int N) {
    __shared__ int sdata[256];
    const int b = blockIdx.x, t = threadIdx.x;
    const int base = b * 1024 + t * 4;
    int v[4], s = 0;
#pragma unroll
    for (int j = 0; j < 4; ++j) { v[j] = (base + j < N) ? indeg[base + j] : 0; s += v[j]; }
    sdata[t] = s;
    __syncthreads();
    for (int off = 1; off < 256; off <<= 1) {
        int x = (t >= off) ? sdata[t - off] : 0;
        __syncthreads();
        sdata[t] += x;
        __syncthreads();
    }
    int run = (t > 0) ? sdata[t - 1] : 0;
    if (t == 255) partials[b] = sdata[255];
#pragma unroll
    for (int j = 0; j < 4; ++j) {
        if (base + j < N) rowptr[base + j] = run;
        run += v[j];
    }
}

__global__ __launch_bounds__(256) void k_scan2(int* __restrict__ partials, int nb) {
    __shared__ int sdata[256];
    int t = threadIdx.x;
    sdata[t] = (t < nb) ? partials[t] : 0;
    __syncthreads();
    for (int off = 1; off < 256; off <<= 1) {
        int x = (t >= off) ? sdata[t - off] : 0;
        __syncthreads();
        sdata[t] += x;
        __syncthreads();
    }
    if (t < nb) partials[t] = (t > 0) ? sdata[t - 1] : 0;
}

__global__ __launch_bounds__(256) void k_scan3(int* __restrict__ rowptr,
                                               const int* __restrict__ partials,
                                               int N, int E) {
    for (int i = blockIdx.x * 256 + threadIdx.x; i < N; i += gridDim.x * 256)
        rowptr[i] += partials[i >> 10];
    if (blockIdx.x == 0 && threadIdx.x == 0) rowptr[N] = E;
}

// ---- CSR fill: colsrc + precomputed edge norm ------------------------------
__global__ __launch_bounds__(256) void k_fill(const int* __restrict__ src,
                                              const int* __restrict__ dst,
                                              const int* __restrict__ rowptr,
                                              const float* __restrict__ dinv,
                                              int* __restrict__ fillcnt,
                                              int* __restrict__ colsrc,
                                              float* __restrict__ colnorm, int E) {
    for (int e = blockIdx.x * 256 + threadIdx.x; e < E; e += gridDim.x * 256) {
        int d = dst[e], s = src[e];
        int pos = rowptr[d] + atomicAdd(&fillcnt[d], 1);
        colsrc[pos]  = s;
        colnorm[pos] = dinv[s] * dinv[d];
    }
}

// ---- weight transpose + hi/lo split: Wt[n][k] = split(W[k][n]) -------------
__global__ __launch_bounds__(256) void k_wsplit(const float* __restrict__ W,
                                                ushort_t* __restrict__ Wh,
                                                ushort_t* __restrict__ Wl,
                                                int K, int Nn) {
    int idx = blockIdx.x * 256 + threadIdx.x;
    if (idx >= K * Nn) return;
    int k = idx / Nn, n = idx - k * Nn;
    float w = W[idx];
    ushort_t h = f2bf(w);
    ushort_t l = f2bf(w - bf2f(h));
    Wh[(size_t)n * K + k] = h;
    Wl[(size_t)n * K + k] = l;
}

// ---- gather aggregation -> split-bf16 planes, 4-deep unroll ----------------
// oh/ol[i,:] = split( dinv[i]^2 z[i,:] + sum_e colnorm[e] z[colsrc[e],:] )
// one wave per node; lane owns VE consecutive floats.
template <int C>
__global__ __launch_bounds__(256) void k_aggregate(const float* __restrict__ z,
                                                   const int* __restrict__ rowptr,
                                                   const int* __restrict__ colsrc,
                                                   const float* __restrict__ colnorm,
                                                   const float* __restrict__ dinv,
                                                   ushort_t* __restrict__ oh,
                                                   ushort_t* __restrict__ ol, int N) {
    constexpr int VE = C / 64;   // 2 or 4 floats per lane
    const int node = (int)(((size_t)blockIdx.x * 256 + threadIdx.x) >> 6);
    const int lane = threadIdx.x & 63;
    if (node >= N) return;
    const float di = dinv[node];
    float a0[VE], a1[VE], a2[VE], a3[VE];
    {
        const float s2 = di * di;
        const float* zp = &z[(size_t)node * C + lane * VE];
#pragma unroll
        for (int j = 0; j < VE; ++j) { a0[j] = zp[j] * s2; a1[j] = a2[j] = a3[j] = 0.f; }
    }
    const int start = rowptr[node], end = rowptr[node + 1];
    for (int base = start; base < end; base += 64) {
        const int rem = end - base;
        int sv = 0; float nv = 0.f;
        if (lane < rem) { sv = colsrc[base + lane]; nv = colnorm[base + lane]; }
        const int cnt = rem < 64 ? rem : 64;
        int jj = 0;
        for (; jj + 4 <= cnt; jj += 4) {
            int   s0 = __shfl(sv, jj),      s1 = __shfl(sv, jj + 1);
            int   s2i = __shfl(sv, jj + 2), s3 = __shfl(sv, jj + 3);
            float n0 = __shfl(nv, jj),      n1 = __shfl(nv, jj + 1);
            float n2 = __shfl(nv, jj + 2),  n3 = __shfl(nv, jj + 3);
            if (VE == 4) {
                float4 v0 = *(const float4*)&z[(size_t)s0 * C + lane * 4];
                float4 v1 = *(const float4*)&z[(size_t)s1 * C + lane * 4];
                float4 v2 = *(const float4*)&z[(size_t)s2i * C + lane * 4];
                float4 v3 = *(const float4*)&z[(size_t)s3 * C + lane * 4];
                a0[0] = fmaf(v0.x, n0, a0[0]); a0[1] = fmaf(v0.y, n0, a0[1]);
                a0[2] = fmaf(v0.z, n0, a0[2]); a0[3] = fmaf(v0.w, n0, a0[3]);
                a1[0] = fmaf(v1.x, n1, a1[0]); a1[1] = fmaf(v1.y, n1, a1[1]);
                a1[2] = fmaf(v1.z, n1, a1[2]); a1[3] = fmaf(v1.w, n1, a1[3]);
                a2[0] = fmaf(v2.x, n2, a2[0]); a2[1] = fmaf(v2.y, n2, a2[1]);
                a2[2] = fmaf(v2.z, n2, a2[2]); a2[3] = fmaf(v2.w, n2, a2[3]);
                a3[0] = fmaf(v3.x, n3, a3[0]); a3[1] = fmaf(v3.y, n3, a3[1]);
                a3[2] = fmaf(v3.z, n3, a3[2]); a3[3] = fmaf(v3.w, n3, a3[3]);
            } else {
                float2 v0 = *(const float2*)&z[(size_t)s0 * C + lane * 2];
                float2 v1 = *(const float2*)&z[(size_t)s1 * C + lane * 2];
                float2 v2 = *(const float2*)&z[(size_t)s2i * C + lane * 2];
                float2 v3 = *(const float2*)&z[(size_t)s3 * C + lane * 2];
                a0[0] = fmaf(v0.x, n0, a0[0]); a0[1] = fmaf(v0.y, n0, a0[1]);
                a1[0] = fmaf(v1.x, n1, a1[0]); a1[1] = fmaf(v1.y, n1, a1[1]);
                a2[0] = fmaf(v2.x, n2, a2[0]); a2[1] = fmaf(v2.y, n2, a2[1]);
                a3[0] = fmaf(v3.x, n3, a3[0]); a3[1] = fmaf(v3.y, n3, a3[1]);
            }
        }
        for (; jj < cnt; ++jj) {
            int   s0 = __shfl(sv, jj);
            float n0 = __shfl(nv, jj);
            const float* p0 = &z[(size_t)s0 * C + lane * VE];
            if (VE == 4) {
                float4 v0 = *(const float4*)p0;
                a0[0] = fmaf(v0.x, n0, a0[0]); a0[1] = fmaf(v0.y, n0, a0[1]);
                a0[2] = fmaf(v0.z, n0, a0[2]); a0[3] = fmaf(v0.w, n0, a0[3]);
            } else {
                float2 v0 = *(const float2*)p0;
                a0[0] = fmaf(v0.x, n0, a0[0]); a0[1] = fmaf(v0.y, n0, a0[1]);
            }
        }
    }
    ushort_t h[VE], l[VE];
#pragma unroll
    for (int j = 0; j < VE; ++j) {
        float a = (a0[j] + a1[j]) + (a2[j] + a3[j]);
        h[j] = f2bf(a);
        l[j] = f2bf(a - bf2f(h[j]));
    }
    size_t ob = (size_t)node * C + lane * VE;
    if (VE == 4) {
        uint2 hv, lv;
        hv.x = (uint_t)h[0] | ((uint_t)h[1] << 16);
        hv.y = (uint_t)h[2] | ((uint_t)h[3] << 16);
        lv.x = (uint_t)l[0] | ((uint_t)l[1] << 16);
        lv.y = (uint_t)l[2] | ((uint_t)l[3] << 16);
        *(uint2*)&oh[ob] = hv;
        *(uint2*)&ol[ob] = lv;
    } else {
        *(uint_t*)&oh[ob] = (uint_t)h[0] | ((uint_t)h[1] << 16);
        *(uint_t*)&ol[ob] = (uint_t)l[0] | ((uint_t)l[1] << 16);
    }
}

// ---- split-bf16 MFMA GEMM, fused bias+ReLU (validated round 2) -------------
// C[M,Nn] = relu((Ah+Al)[M,K] @ (Wh+Wl)^T_as_[Nn,K] + bias), 3-pass split.
// BM=BN=128, BK=64, 4 waves (2x2), wave tile 64x64 = 4x4 MFMA 16x16x32.
__global__ __launch_bounds__(256, 2) void k_gemm_mfma(
    const ushort_t* __restrict__ Ah, const ushort_t* __restrict__ Al,
    const ushort_t* __restrict__ Bh, const ushort_t* __restrict__ Bl,
    const float* __restrict__ bias, float* __restrict__ C,
    int M, int K, int Nn) {
    __shared__ ushort_t As[2][128][72];   // [plane][m][k] pad 64->72 (bank spread)
    __shared__ ushort_t Bs[2][128][72];   // [plane][n][k]
    const int tid  = threadIdx.x;
    const int lane = tid & 63;
    const int wid  = tid >> 6;
    const int wr   = wid >> 1, wc = wid & 1;
    const int bm   = blockIdx.x * 128;
    const int bn   = blockIdx.y * 128;
    const int srow = tid >> 3;            // 0..31 (stage row base)
    const int sk8  = tid & 7;             // 16B segment within row

    f32x4 acc[4][4] = {};

    for (int kt = 0; kt < K; kt += 64) {
        __syncthreads();
#pragma unroll
        for (int j = 0; j < 4; ++j) {
            int row = srow + j * 32;
            uint4 vh = make_uint4(0, 0, 0, 0), vl = vh;
            int gr = bm + row;
            if (gr < M) {
                vh = *(const uint4*)&Ah[(size_t)gr * K + kt + sk8 * 8];
                vl = *(const uint4*)&Al[(size_t)gr * K + kt + sk8 * 8];
            }
            *(uint4*)&As[0][row][sk8 * 8] = vh;
            *(uint4*)&As[1][row][sk8 * 8] = vl;
            uint4 wh = *(const uint4*)&Bh[(size_t)(bn + row) * K + kt + sk8 * 8];
            uint4 wl = *(const uint4*)&Bl[(size_t)(bn + row) * K + kt + sk8 * 8];
            *(uint4*)&Bs[0][row][sk8 * 8] = wh;
            *(uint4*)&Bs[1][row][sk8 * 8] = wl;
        }
        __syncthreads();
#pragma unroll
        for (int ks = 0; ks < 2; ++ks) {
            const int acol = ks * 32 + ((lane >> 4) << 3);
            const int ar   = (wr << 6) + (lane & 15);
            const int br   = (wc << 6) + (lane & 15);
            bf16x8 ah[4], al[4], bh[4], bl[4];
#pragma unroll
            for (int t4 = 0; t4 < 4; ++t4) {
                ah[t4] = *(const bf16x8*)&As[0][ar + t4 * 16][acol];
                al[t4] = *(const bf16x8*)&As[1][ar + t4 * 16][acol];
                bh[t4] = *(const bf16x8*)&Bs[0][br + t4 * 16][acol];
                bl[t4] = *(const bf16x8*)&Bs[1][br + t4 * 16][acol];
            }
#pragma unroll
            for (int mt = 0; mt < 4; ++mt)
#pragma unroll
                for (int nt = 0; nt < 4; ++nt) {
                    acc[mt][nt] = __builtin_amdgcn_mfma_f32_16x16x32_bf16(
                        ah[mt], bh[nt], acc[mt][nt], 0, 0, 0);
                    acc[mt][nt] = __builtin_amdgcn_mfma_f32_16x16x32_bf16(
                        ah[mt], bl[nt], acc[mt][nt], 0, 0, 0);
                    acc[mt][nt] = __builtin_amdgcn_mfma_f32_16x16x32_bf16(
                        al[mt], bh[nt], acc[mt][nt], 0, 0, 0);
                }
        }
    }

    // epilogue: D layout col=lane&15, row=(lane>>4)*4+reg
    const int col0  = bn + (wc << 6) + (lane & 15);
    const int rbase = bm + (wr << 6) + ((lane >> 4) << 2);
    float bv[4];
#pragma unroll
    for (int nt = 0; nt < 4; ++nt) bv[nt] = bias[col0 + nt * 16];
#pragma unroll
    for (int mt = 0; mt < 4; ++mt)
#pragma unroll
        for (int j = 0; j < 4; ++j) {
            int r = rbase + mt * 16 + j;
            if (r < M) {
                float* cp = &C[(size_t)r * Nn + col0];
#pragma unroll
                for (int nt = 0; nt < 4; ++nt)
                    cp[nt * 16] = fmaxf(acc[mt][nt][j] + bv[nt], 0.f);
            }
        }
}

extern "C" void kernel_launch(void* const* d_in, const int* in_sizes, int n_in,
                              void* d_out, int out_size, void* d_ws, size_t ws_size,
                              hipStream_t stream) {
    const float* x  = (const float*)d_in[0];
    const int*   ei = (const int*)d_in[1];
    const float* W0 = (const float*)d_in[2];
    const float* b0 = (const float*)d_in[3];
    const float* W1 = (const float*)d_in[4];
    const float* b1 = (const float*)d_in[5];
    const float* W2 = (const float*)d_in[6];
    const float* b2 = (const float*)d_in[7];

    const int D = 128, H = 256;
    const int N = in_sizes[0] / D;
    const int E = in_sizes[1] / 2;

    char* ws = (char*)d_ws;
    auto align = [](size_t v) { return (v + 511) & ~(size_t)511; };
    size_t o = 0;
    int*      flag     = (int*)(ws + o);      o += align(sizeof(int));
    float*    dinv     = (float*)(ws + o);    o += align((size_t)N * 4);
    int*      indeg    = (int*)(ws + o);      o += align((size_t)N * 4);
    int*      fillcnt  = (int*)(ws + o);      o += align((size_t)N * 4);
    int*      rowptr   = (int*)(ws + o);      o += align(((size_t)N + 1) * 4);
    int*      partials = (int*)(ws + o);      o += align(256 * 4);
    int*      src32    = (int*)(ws + o);      o += align((size_t)E * 4);
    int*      dst32    = (int*)(ws + o);      o += align((size_t)E * 4);
    int*      colsrc   = (int*)(ws + o);      o += align((size_t)E * 4);
    float*    colnorm  = (float*)(ws + o);    o += align((size_t)E * 4);
    ushort_t* Wth      = (ushort_t*)(ws + o); o += align((size_t)H * H * 2);
    ushort_t* Wtl      = (ushort_t*)(ws + o); o += align((size_t)H * H * 2);
    ushort_t* Wth2     = (ushort_t*)(ws + o); o += align((size_t)H * H * 2);
    ushort_t* Wtl2     = (ushort_t*)(ws + o); o += align((size_t)H * H * 2);
    ushort_t* Wth3     = (ushort_t*)(ws + o); o += align((size_t)H * H * 2);
    ushort_t* Wtl3     = (ushort_t*)(ws + o); o += align((size_t)H * H * 2);
    ushort_t* Ah       = (ushort_t*)(ws + o); o += align((size_t)N * H * 2);
    ushort_t* Al       = (ushort_t*)(ws + o); o += align((size_t)N * H * 2);
    float*    bufB     = (float*)(ws + o);    o += align((size_t)N * H * 4);
    float*    out      = (float*)d_out;

    const int nBlkN  = (N + 255) / 256;
    const int nBlkE  = (E + 255) / 256;
    const int nbScan = (N + 1023) / 1024;

    // ---- normalization + CSR build (colnorm precomputed) ----
    k_detect<<<1, 256, 0, stream>>>(ei, E, flag);
    k_convert<<<nBlkE, 256, 0, stream>>>(ei, E, flag, src32, dst32);
    k_zero_int<<<nBlkN, 256, 0, stream>>>(indeg, N);
    k_zero_int<<<nBlkN, 256, 0, stream>>>(fillcnt, N);
    k_count<<<nBlkE, 256, 0, stream>>>(dst32, indeg, E);
    k_dinv<<<nBlkN, 256, 0, stream>>>(indeg, dinv, N);
    k_scan1<<<nbScan, 256, 0, stream>>>(indeg, rowptr, partials, N);
    k_scan2<<<1, 256, 0, stream>>>(partials, nbScan);
    k_scan3<<<nBlkN, 256, 0, stream>>>(rowptr, partials, N, E);
    k_fill<<<nBlkE, 256, 0, stream>>>(src32, dst32, rowptr, dinv, fillcnt,
                                      colsrc, colnorm, E);

    // ---- weight splits (tiny; all up front) ----
    k_wsplit<<<(D * H + 255) / 256, 256, 0, stream>>>(W0, Wth, Wtl, D, H);
    k_wsplit<<<(H * H + 255) / 256, 256, 0, stream>>>(W1, Wth2, Wtl2, H, H);
    k_wsplit<<<(H * H + 255) / 256, 256, 0, stream>>>(W2, Wth3, Wtl3, H, H);

    const int aggBlk = (N * 64 + 255) / 256;     // one wave per node
    dim3 gemmGrid((N + 127) / 128, H / 128);

    // ---- layer 0 ----
    k_aggregate<128><<<aggBlk, 256, 0, stream>>>(x, rowptr, colsrc, colnorm,
                                                 dinv, Ah, Al, N);
    k_gemm_mfma<<<gemmGrid, 256, 0, stream>>>(Ah, Al, Wth, Wtl, b0, bufB, N, D, H);

    // ---- layer 1 ----
    k_aggregate<256><<<aggBlk, 256, 0, stream>>>(bufB, rowptr, colsrc, colnorm,
                                                 dinv, Ah, Al, N);
    k_gemm_mfma<<<gemmGrid, 256, 0, stream>>>(Ah, Al, Wth2, Wtl2, b1, bufB, N, H, H);

    // ---- layer 2 ----
    k_aggregate<256><<<aggBlk, 256, 0, stream>>>(bufB, rowptr, colsrc, colnorm,
                                                 dinv, Ah, Al, N);
    k_gemm_mfma<<<gemmGrid, 256, 0, stream>>>(Ah, Al, Wth3, Wtl3, b2, out, N, H, H);

    (void)n_in; (void)out_size; (void)ws_size; (void)o;
}

// Round 10
// 585.101 us; speedup vs baseline: 1.3992x; 1.1997x over previous
//
#include <hip/hip_runtime.h>
#include <hip/hip_fp16.h>

// ---------------------------------------------------------------------------
// 3-layer GCN, reassociated:  Z_{l+1} = relu( (A_hat · Z_l) @ W_l + b_l )
// A_hat = D^-1/2 (A+I) D^-1/2. CSR gather aggregation, colnorm precomputed.
// Intermediate activations stored fp16 (halves the random-gather bytes; the
// gather path is memory-path-bound at ~4 TB/s, so bytes == time).
// GEMM = split-bf16 MFMA (3-pass hi/lo emulation of fp32, err ~2^-16).
// ---------------------------------------------------------------------------

typedef __bf16 bf16x8 __attribute__((ext_vector_type(8)));
typedef float  f32x4  __attribute__((ext_vector_type(4)));
typedef unsigned short ushort_t;
typedef unsigned int   uint_t;

__device__ __forceinline__ ushort_t f2bf(float f) {
    uint_t u = __builtin_bit_cast(uint_t, f);
    u += 0x7FFFu + ((u >> 16) & 1u);       // RNE
    return (ushort_t)(u >> 16);
}
__device__ __forceinline__ float bf2f(ushort_t h) {
    uint_t u = ((uint_t)h) << 16;
    return __builtin_bit_cast(float, u);
}
__device__ __forceinline__ float4 h4_to_f4(uint2 u) {
    __half2 a = __builtin_bit_cast(__half2, u.x);
    __half2 b = __builtin_bit_cast(__half2, u.y);
    float2 fa = __half22float2(a);
    float2 fb = __half22float2(b);
    return make_float4(fa.x, fa.y, fb.x, fb.y);
}

// ---- edge dtype detection: int64 edges have all-zero high words ------------
__global__ void k_detect(const int* __restrict__ ei, int E, int* __restrict__ flag) {
    __shared__ int nonzero;
    if (threadIdx.x == 0) nonzero = 0;
    __syncthreads();
    size_t k = (size_t)threadIdx.x * (size_t)E / 256;
    if (ei[2 * k + 1] != 0) atomicOr(&nonzero, 1);
    __syncthreads();
    if (threadIdx.x == 0) *flag = (nonzero == 0) ? 1 : 0;   // 1 => int64
}

__global__ __launch_bounds__(256) void k_convert(const int* __restrict__ ei, int E,
                                                 const int* __restrict__ flag,
                                                 int* __restrict__ src32,
                                                 int* __restrict__ dst32) {
    int is64 = *flag;
    for (int e = blockIdx.x * 256 + threadIdx.x; e < E; e += gridDim.x * 256) {
        if (is64) {
            const long long* p = (const long long*)ei;
            src32[e] = (int)p[e];
            dst32[e] = (int)p[(size_t)E + e];
        } else {
            src32[e] = ei[e];
            dst32[e] = ei[(size_t)E + e];
        }
    }
}

__global__ __launch_bounds__(256) void k_zero_int(int* __restrict__ p, int n) {
    for (int i = blockIdx.x * 256 + threadIdx.x; i < n; i += gridDim.x * 256) p[i] = 0;
}

__global__ __launch_bounds__(256) void k_count(const int* __restrict__ dst,
                                               int* __restrict__ indeg, int E) {
    for (int e = blockIdx.x * 256 + threadIdx.x; e < E; e += gridDim.x * 256)
        atomicAdd(&indeg[dst[e]], 1);
}

__global__ __launch_bounds__(256) void k_dinv(const int* __restrict__ indeg,
                                              float* __restrict__ dinv, int N) {
    int i = blockIdx.x * 256 + threadIdx.x;
    if (i < N) dinv[i] = rsqrtf(1.0f + (float)indeg[i]);   // +1 self-loop
}

// ---- exclusive scan of indeg[N] -> rowptr ----------------------------------
__global__ __launch_bounds__(256) void k_scan1(const int* __restrict__ indeg,
                                               int* __restrict__ rowptr,
                                               int* __restrict__ partials, int N) {
    __shared__ int sdata[256];
    const int b = blockIdx.x, t = threadIdx.x;
    const int base = b * 1024 + t * 4;
    int v[4], s = 0;
#pragma unroll
    for (int j = 0; j < 4; ++j) { v[j] = (base + j < N) ? indeg[base + j] : 0; s += v[j]; }
    sdata[t] = s;
    __syncthreads();
    for (int off = 1; off < 256; off <<= 1) {
        int x = (t >= off) ? sdata[t - off] : 0;
        __syncthreads();
        sdata[t] += x;
        __syncthreads();
    }
    int run = (t > 0) ? sdata[t - 1] : 0;
    if (t == 255) partials[b] = sdata[255];
#pragma unroll
    for (int j = 0; j < 4; ++j) {
        if (base + j < N) rowptr[base + j] = run;
        run += v[j];
    }
}

__global__ __launch_bounds__(256) void k_scan2(int* __restrict__ partials, int nb) {
    __shared__ int sdata[256];
    int t = threadIdx.x;
    sdata[t] = (t < nb) ? partials[t] : 0;
    __syncthreads();
    for (int off = 1; off < 256; off <<= 1) {
        int x = (t >= off) ? sdata[t - off] : 0;
        __syncthreads();
        sdata[t] += x;
        __syncthreads();
    }
    if (t < nb) partials[t] = (t > 0) ? sdata[t - 1] : 0;
}

__global__ __launch_bounds__(256) void k_scan3(int* __restrict__ rowptr,
                                               const int* __restrict__ partials,
                                               int N, int E) {
    for (int i = blockIdx.x * 256 + threadIdx.x; i < N; i += gridDim.x * 256)
        rowptr[i] += partials[i >> 10];
    if (blockIdx.x == 0 && threadIdx.x == 0) rowptr[N] = E;
}

// ---- CSR fill: colsrc + precomputed edge norm ------------------------------
__global__ __launch_bounds__(256) void k_fill(const int* __restrict__ src,
                                              const int* __restrict__ dst,
                                              const int* __restrict__ rowptr,
                                              const float* __restrict__ dinv,
                                              int* __restrict__ fillcnt,
                                              int* __restrict__ colsrc,
                                              float* __restrict__ colnorm, int E) {
    for (int e = blockIdx.x * 256 + threadIdx.x; e < E; e += gridDim.x * 256) {
        int d = dst[e], s = src[e];
        int pos = rowptr[d] + atomicAdd(&fillcnt[d], 1);
        colsrc[pos]  = s;
        colnorm[pos] = dinv[s] * dinv[d];
    }
}

// ---- weight transpose + hi/lo split: Wt[n][k] = split(W[k][n]) -------------
__global__ __launch_bounds__(256) void k_wsplit(const float* __restrict__ W,
                                                ushort_t* __restrict__ Wh,
                                                ushort_t* __restrict__ Wl,
                                                int K, int Nn) {
    int idx = blockIdx.x * 256 + threadIdx.x;
    if (idx >= K * Nn) return;
    int k = idx / Nn, n = idx - k * Nn;
    float w = W[idx];
    ushort_t h = f2bf(w);
    ushort_t l = f2bf(w - bf2f(h));
    Wh[(size_t)n * K + k] = h;
    Wl[(size_t)n * K + k] = l;
}

// ---- layer-0 aggregation (fp32 input x, C=128) -> split-bf16 planes --------
// one wave per node; lane owns 2 consecutive floats; 2-deep unroll.
__global__ __launch_bounds__(256) void k_agg_f32(const float* __restrict__ z,
                                                 const int* __restrict__ rowptr,
                                                 const int* __restrict__ colsrc,
                                                 const float* __restrict__ colnorm,
                                                 const float* __restrict__ dinv,
                                                 ushort_t* __restrict__ oh,
                                                 ushort_t* __restrict__ ol, int N) {
    constexpr int C = 128;
    const int node = (int)(((size_t)blockIdx.x * 256 + threadIdx.x) >> 6);
    const int lane = threadIdx.x & 63;
    if (node >= N) return;
    const float di = dinv[node];
    float a0[2], a1[2];
    {
        const float s2 = di * di;
        float2 zv = *(const float2*)&z[(size_t)node * C + lane * 2];
        a0[0] = zv.x * s2; a0[1] = zv.y * s2; a1[0] = a1[1] = 0.f;
    }
    const int start = rowptr[node], end = rowptr[node + 1];
    for (int base = start; base < end; base += 64) {
        const int rem = end - base;
        int sv = 0; float nv = 0.f;
        if (lane < rem) { sv = colsrc[base + lane]; nv = colnorm[base + lane]; }
        const int cnt = rem < 64 ? rem : 64;
        int jj = 0;
        for (; jj + 2 <= cnt; jj += 2) {
            int   s0 = __shfl(sv, jj),  s1 = __shfl(sv, jj + 1);
            float n0 = __shfl(nv, jj),  n1 = __shfl(nv, jj + 1);
            float2 v0 = *(const float2*)&z[(size_t)s0 * C + lane * 2];
            float2 v1 = *(const float2*)&z[(size_t)s1 * C + lane * 2];
            a0[0] = fmaf(v0.x, n0, a0[0]); a0[1] = fmaf(v0.y, n0, a0[1]);
            a1[0] = fmaf(v1.x, n1, a1[0]); a1[1] = fmaf(v1.y, n1, a1[1]);
        }
        if (jj < cnt) {
            int   s0 = __shfl(sv, jj);
            float n0 = __shfl(nv, jj);
            float2 v0 = *(const float2*)&z[(size_t)s0 * C + lane * 2];
            a0[0] = fmaf(v0.x, n0, a0[0]); a0[1] = fmaf(v0.y, n0, a0[1]);
        }
    }
    ushort_t h[2], l[2];
#pragma unroll
    for (int j = 0; j < 2; ++j) {
        float a = a0[j] + a1[j];
        h[j] = f2bf(a);
        l[j] = f2bf(a - bf2f(h[j]));
    }
    size_t ob = (size_t)node * C + lane * 2;
    *(uint_t*)&oh[ob] = (uint_t)h[0] | ((uint_t)h[1] << 16);
    *(uint_t*)&ol[ob] = (uint_t)l[0] | ((uint_t)l[1] << 16);
}

// ---- layers 1,2 aggregation (fp16 input z16, C=256) -> split-bf16 planes ---
// one wave per node; lane owns 4 consecutive cols (8B fp16 load); 2-deep.
__global__ __launch_bounds__(256) void k_agg_f16(const __half* __restrict__ z,
                                                 const int* __restrict__ rowptr,
                                                 const int* __restrict__ colsrc,
                                                 const float* __restrict__ colnorm,
                                                 const float* __restrict__ dinv,
                                                 ushort_t* __restrict__ oh,
                                                 ushort_t* __restrict__ ol, int N) {
    constexpr int C = 256;
    const int node = (int)(((size_t)blockIdx.x * 256 + threadIdx.x) >> 6);
    const int lane = threadIdx.x & 63;
    if (node >= N) return;
    const float di = dinv[node];
    float a0[4], a1[4];
    {
        const float s2 = di * di;
        float4 zv = h4_to_f4(*(const uint2*)&z[(size_t)node * C + lane * 4]);
        a0[0] = zv.x * s2; a0[1] = zv.y * s2; a0[2] = zv.z * s2; a0[3] = zv.w * s2;
        a1[0] = a1[1] = a1[2] = a1[3] = 0.f;
    }
    const int start = rowptr[node], end = rowptr[node + 1];
    for (int base = start; base < end; base += 64) {
        const int rem = end - base;
        int sv = 0; float nv = 0.f;
        if (lane < rem) { sv = colsrc[base + lane]; nv = colnorm[base + lane]; }
        const int cnt = rem < 64 ? rem : 64;
        int jj = 0;
        for (; jj + 2 <= cnt; jj += 2) {
            int   s0 = __shfl(sv, jj),  s1 = __shfl(sv, jj + 1);
            float n0 = __shfl(nv, jj),  n1 = __shfl(nv, jj + 1);
            uint2 u0 = *(const uint2*)&z[(size_t)s0 * C + lane * 4];
            uint2 u1 = *(const uint2*)&z[(size_t)s1 * C + lane * 4];
            float4 v0 = h4_to_f4(u0);
            float4 v1 = h4_to_f4(u1);
            a0[0] = fmaf(v0.x, n0, a0[0]); a0[1] = fmaf(v0.y, n0, a0[1]);
            a0[2] = fmaf(v0.z, n0, a0[2]); a0[3] = fmaf(v0.w, n0, a0[3]);
            a1[0] = fmaf(v1.x, n1, a1[0]); a1[1] = fmaf(v1.y, n1, a1[1]);
            a1[2] = fmaf(v1.z, n1, a1[2]); a1[3] = fmaf(v1.w, n1, a1[3]);
        }
        if (jj < cnt) {
            int   s0 = __shfl(sv, jj);
            float n0 = __shfl(nv, jj);
            float4 v0 = h4_to_f4(*(const uint2*)&z[(size_t)s0 * C + lane * 4]);
            a0[0] = fmaf(v0.x, n0, a0[0]); a0[1] = fmaf(v0.y, n0, a0[1]);
            a0[2] = fmaf(v0.z, n0, a0[2]); a0[3] = fmaf(v0.w, n0, a0[3]);
        }
    }
    ushort_t h[4], l[4];
#pragma unroll
    for (int j = 0; j < 4; ++j) {
        float a = a0[j] + a1[j];
        h[j] = f2bf(a);
        l[j] = f2bf(a - bf2f(h[j]));
    }
    size_t ob = (size_t)node * C + lane * 4;
    uint2 hv, lv;
    hv.x = (uint_t)h[0] | ((uint_t)h[1] << 16);
    hv.y = (uint_t)h[2] | ((uint_t)h[3] << 16);
    lv.x = (uint_t)l[0] | ((uint_t)l[1] << 16);
    lv.y = (uint_t)l[2] | ((uint_t)l[3] << 16);
    *(uint2*)&oh[ob] = hv;
    *(uint2*)&ol[ob] = lv;
}

// ---- split-bf16 MFMA GEMM, fused bias+ReLU; OutT = __half (mid) / float ----
// C[M,Nn] = relu((Ah+Al)[M,K] @ (Wh+Wl)^T_as_[Nn,K] + bias), 3-pass split.
// BM=BN=128, BK=64, 4 waves (2x2), wave tile 64x64 = 4x4 MFMA 16x16x32.
template <typename OutT>
__global__ __launch_bounds__(256, 2) void k_gemm_mfma(
    const ushort_t* __restrict__ Ah, const ushort_t* __restrict__ Al,
    const ushort_t* __restrict__ Bh, const ushort_t* __restrict__ Bl,
    const float* __restrict__ bias, OutT* __restrict__ C,
    int M, int K, int Nn) {
    __shared__ ushort_t As[2][128][72];   // [plane][m][k] pad 64->72 (bank spread)
    __shared__ ushort_t Bs[2][128][72];   // [plane][n][k]
    const int tid  = threadIdx.x;
    const int lane = tid & 63;
    const int wid  = tid >> 6;
    const int wr   = wid >> 1, wc = wid & 1;
    const int bm   = blockIdx.x * 128;
    const int bn   = blockIdx.y * 128;
    const int srow = tid >> 3;            // 0..31 (stage row base)
    const int sk8  = tid & 7;             // 16B segment within row

    f32x4 acc[4][4] = {};

    for (int kt = 0; kt < K; kt += 64) {
        __syncthreads();
#pragma unroll
        for (int j = 0; j < 4; ++j) {
            int row = srow + j * 32;
            uint4 vh = make_uint4(0, 0, 0, 0), vl = vh;
            int gr = bm + row;
            if (gr < M) {
                vh = *(const uint4*)&Ah[(size_t)gr * K + kt + sk8 * 8];
                vl = *(const uint4*)&Al[(size_t)gr * K + kt + sk8 * 8];
            }
            *(uint4*)&As[0][row][sk8 * 8] = vh;
            *(uint4*)&As[1][row][sk8 * 8] = vl;
            uint4 wh = *(const uint4*)&Bh[(size_t)(bn + row) * K + kt + sk8 * 8];
            uint4 wl = *(const uint4*)&Bl[(size_t)(bn + row) * K + kt + sk8 * 8];
            *(uint4*)&Bs[0][row][sk8 * 8] = wh;
            *(uint4*)&Bs[1][row][sk8 * 8] = wl;
        }
        __syncthreads();
#pragma unroll
        for (int ks = 0; ks < 2; ++ks) {
            const int acol = ks * 32 + ((lane >> 4) << 3);
            const int ar   = (wr << 6) + (lane & 15);
            const int br   = (wc << 6) + (lane & 15);
            bf16x8 ah[4], al[4], bh[4], bl[4];
#pragma unroll
            for (int t4 = 0; t4 < 4; ++t4) {
                ah[t4] = *(const bf16x8*)&As[0][ar + t4 * 16][acol];
                al[t4] = *(const bf16x8*)&As[1][ar + t4 * 16][acol];
                bh[t4] = *(const bf16x8*)&Bs[0][br + t4 * 16][acol];
                bl[t4] = *(const bf16x8*)&Bs[1][br + t4 * 16][acol];
            }
#pragma unroll
            for (int mt = 0; mt < 4; ++mt)
#pragma unroll
                for (int nt = 0; nt < 4; ++nt) {
                    acc[mt][nt] = __builtin_amdgcn_mfma_f32_16x16x32_bf16(
                        ah[mt], bh[nt], acc[mt][nt], 0, 0, 0);
                    acc[mt][nt] = __builtin_amdgcn_mfma_f32_16x16x32_bf16(
                        ah[mt], bl[nt], acc[mt][nt], 0, 0, 0);
                    acc[mt][nt] = __builtin_amdgcn_mfma_f32_16x16x32_bf16(
                        al[mt], bh[nt], acc[mt][nt], 0, 0, 0);
                }
        }
    }

    // epilogue: D layout col=lane&15, row=(lane>>4)*4+reg
    const int col0  = bn + (wc << 6) + (lane & 15);
    const int rbase = bm + (wr << 6) + ((lane >> 4) << 2);
    float bv[4];
#pragma unroll
    for (int nt = 0; nt < 4; ++nt) bv[nt] = bias[col0 + nt * 16];
#pragma unroll
    for (int mt = 0; mt < 4; ++mt)
#pragma unroll
        for (int j = 0; j < 4; ++j) {
            int r = rbase + mt * 16 + j;
            if (r < M) {
                OutT* cp = &C[(size_t)r * Nn + col0];
#pragma unroll
                for (int nt = 0; nt < 4; ++nt) {
                    float v = fmaxf(acc[mt][nt][j] + bv[nt], 0.f);
                    if constexpr (sizeof(OutT) == 2)
                        cp[nt * 16] = __float2half_rn(v);
                    else
                        cp[nt * 16] = v;
                }
            }
        }
}

extern "C" void kernel_launch(void* const* d_in, const int* in_sizes, int n_in,
                              void* d_out, int out_size, void* d_ws, size_t ws_size,
                              hipStream_t stream) {
    const float* x  = (const float*)d_in[0];
    const int*   ei = (const int*)d_in[1];
    const float* W0 = (const float*)d_in[2];
    const float* b0 = (const float*)d_in[3];
    const float* W1 = (const float*)d_in[4];
    const float* b1 = (const float*)d_in[5];
    const float* W2 = (const float*)d_in[6];
    const float* b2 = (const float*)d_in[7];

    const int D = 128, H = 256;
    const int N = in_sizes[0] / D;
    const int E = in_sizes[1] / 2;

    char* ws = (char*)d_ws;
    auto align = [](size_t v) { return (v + 511) & ~(size_t)511; };
    size_t o = 0;
    int*      flag     = (int*)(ws + o);      o += align(sizeof(int));
    float*    dinv     = (float*)(ws + o);    o += align((size_t)N * 4);
    int*      indeg    = (int*)(ws + o);      o += align((size_t)N * 4);
    int*      fillcnt  = (int*)(ws + o);      o += align((size_t)N * 4);
    int*      rowptr   = (int*)(ws + o);      o += align(((size_t)N + 1) * 4);
    int*      partials = (int*)(ws + o);      o += align(256 * 4);
    int*      src32    = (int*)(ws + o);      o += align((size_t)E * 4);
    int*      dst32    = (int*)(ws + o);      o += align((size_t)E * 4);
    int*      colsrc   = (int*)(ws + o);      o += align((size_t)E * 4);
    float*    colnorm  = (float*)(ws + o);    o += align((size_t)E * 4);
    ushort_t* Wth      = (ushort_t*)(ws + o); o += align((size_t)H * H * 2);
    ushort_t* Wtl      = (ushort_t*)(ws + o); o += align((size_t)H * H * 2);
    ushort_t* Wth2     = (ushort_t*)(ws + o); o += align((size_t)H * H * 2);
    ushort_t* Wtl2     = (ushort_t*)(ws + o); o += align((size_t)H * H * 2);
    ushort_t* Wth3     = (ushort_t*)(ws + o); o += align((size_t)H * H * 2);
    ushort_t* Wtl3     = (ushort_t*)(ws + o); o += align((size_t)H * H * 2);
    ushort_t* Ah       = (ushort_t*)(ws + o); o += align((size_t)N * H * 2);
    ushort_t* Al       = (ushort_t*)(ws + o); o += align((size_t)N * H * 2);
    __half*   z16      = (__half*)(ws + o);   o += align((size_t)N * H * 2);
    float*    out      = (float*)d_out;

    const int nBlkN  = (N + 255) / 256;
    const int nBlkE  = (E + 255) / 256;
    const int nbScan = (N + 1023) / 1024;

    // ---- normalization + CSR build (colnorm precomputed) ----
    k_detect<<<1, 256, 0, stream>>>(ei, E, flag);
    k_convert<<<nBlkE, 256, 0, stream>>>(ei, E, flag, src32, dst32);
    k_zero_int<<<nBlkN, 256, 0, stream>>>(indeg, N);
    k_zero_int<<<nBlkN, 256, 0, stream>>>(fillcnt, N);
    k_count<<<nBlkE, 256, 0, stream>>>(dst32, indeg, E);
    k_dinv<<<nBlkN, 256, 0, stream>>>(indeg, dinv, N);
    k_scan1<<<nbScan, 256, 0, stream>>>(indeg, rowptr, partials, N);
    k_scan2<<<1, 256, 0, stream>>>(partials, nbScan);
    k_scan3<<<nBlkN, 256, 0, stream>>>(rowptr, partials, N, E);
    k_fill<<<nBlkE, 256, 0, stream>>>(src32, dst32, rowptr, dinv, fillcnt,
                                      colsrc, colnorm, E);

    // ---- weight splits (tiny; all up front) ----
    k_wsplit<<<(D * H + 255) / 256, 256, 0, stream>>>(W0, Wth, Wtl, D, H);
    k_wsplit<<<(H * H + 255) / 256, 256, 0, stream>>>(W1, Wth2, Wtl2, H, H);
    k_wsplit<<<(H * H + 255) / 256, 256, 0, stream>>>(W2, Wth3, Wtl3, H, H);

    const int aggBlk = (N * 64 + 255) / 256;     // one wave per node
    dim3 gemmGrid((N + 127) / 128, H / 128);

    // ---- layer 0: agg fp32 x -> A planes; GEMM -> z16 (fp16) ----
    k_agg_f32<<<aggBlk, 256, 0, stream>>>(x, rowptr, colsrc, colnorm,
                                          dinv, Ah, Al, N);
    k_gemm_mfma<__half><<<gemmGrid, 256, 0, stream>>>(Ah, Al, Wth, Wtl, b0,
                                                      z16, N, D, H);

    // ---- layer 1: agg fp16 z16 -> A planes; GEMM -> z16 (safe: agg done) ----
    k_agg_f16<<<aggBlk, 256, 0, stream>>>(z16, rowptr, colsrc, colnorm,
                                          dinv, Ah, Al, N);
    k_gemm_mfma<__half><<<gemmGrid, 256, 0, stream>>>(Ah, Al, Wth2, Wtl2, b1,
                                                      z16, N, H, H);

    // ---- layer 2: agg fp16 z16 -> A planes; GEMM -> fp32 d_out ----
    k_agg_f16<<<aggBlk, 256, 0, stream>>>(z16, rowptr, colsrc, colnorm,
                                          dinv, Ah, Al, N);
    k_gemm_mfma<float><<<gemmGrid, 256, 0, stream>>>(Ah, Al, Wth3, Wtl3, b2,
                                                     out, N, H, H);

    (void)n_in; (void)out_size; (void)ws_size; (void)o;
}